// Round 5
// baseline (281.187 us; speedup 1.0000x reference)
//
#include <hip/hip_runtime.h>
#include <stdint.h>

#define QPF  127.0f
#define MINR 1e-6f

typedef int v4i __attribute__((ext_vector_type(4)));
typedef _Float16 h8 __attribute__((ext_vector_type(8)));
typedef signed char c8 __attribute__((ext_vector_type(8)));

// ---------- helpers ----------
__device__ __forceinline__ float wave_max64(float v) {
  v = fmaxf(v, __shfl_xor(v, 32, 64));
  v = fmaxf(v, __shfl_xor(v, 16, 64));
  v = fmaxf(v, __shfl_xor(v, 8, 64));
  v = fmaxf(v, __shfl_xor(v, 4, 64));
  v = fmaxf(v, __shfl_xor(v, 2, 64));
  v = fmaxf(v, __shfl_xor(v, 1, 64));
  return v;
}

// Exact-GELU via A&S 7.1.26 erf (|eps| <= 1.5e-7), branchless.
__device__ __forceinline__ float gelu_exact(float x) {
  float z = fabsf(x) * 0.70710678118654752440f;
  float t = __builtin_amdgcn_rcpf(fmaf(0.3275911f, z, 1.0f));
  float p = fmaf(fmaf(fmaf(fmaf(1.061405429f, t, -1.453152027f), t,
                           1.421413741f), t, -0.284496736f), t, 0.254829592f) * t;
  float e = __expf(-z * z);
  float erfz = fmaf(-p, e, 1.0f);
  float cdf = fmaf(0.5f, copysignf(erfz, x), 0.5f);
  return x * cdf;
}

// async global->LDS, 16B per lane; LDS dest is wave-uniform base + lane*16
__device__ __forceinline__ void gl2lds16(const void* g, void* l) {
  __builtin_amdgcn_global_load_lds(
      (const __attribute__((address_space(1))) int*)g,
      (__attribute__((address_space(3))) int*)l,
      16, 0, 0);
}

// ---------- fused pre-pass: w1/w2 amax partials + per-token x quant + amaxh zero ----
// blocks [0,512): w1 partial-amax; [512,1024): w2; [1024, 1024+N): token quant.
__global__ __launch_bounds__(256) void pre_kernel(
    const float* __restrict__ w1, const float* __restrict__ w2, int n4,
    const float* __restrict__ x, signed char* __restrict__ qx,
    float* __restrict__ sx, unsigned* __restrict__ amaxh,
    float* __restrict__ partial, int K, int nTok) {
  __shared__ float red[4];
  const int b = blockIdx.x;
  const int tid = threadIdx.x;
  const int lane = tid & 63, wvi = tid >> 6;

  if (b < 1024) {
    const float4* w4 = (const float4*)(b < 512 ? w1 : w2);
    const int bb = b & 511;
    float m = 0.f;
    for (int i = bb * 256 + tid; i < n4; i += 512 * 256) {
      float4 v = w4[i];
      m = fmaxf(m, fmaxf(fmaxf(fabsf(v.x), fabsf(v.y)),
                         fmaxf(fabsf(v.z), fabsf(v.w))));
    }
    m = wave_max64(m);
    if (lane == 0) red[wvi] = m;
    __syncthreads();
    if (tid == 0)
      partial[b] = fmaxf(fmaxf(red[0], red[1]), fmaxf(red[2], red[3]));
  } else {
    const int token = b - 1024;
    const float4* xr = (const float4*)(x + (size_t)token * K);
    const int k4 = K >> 2;   // 192
    float m = 0.f;
    float4 v = {0.f, 0.f, 0.f, 0.f};
    if (tid < k4) {
      v = xr[tid];
      m = fmaxf(fmaxf(fabsf(v.x), fabsf(v.y)), fmaxf(fabsf(v.z), fabsf(v.w)));
    }
    m = wave_max64(m);
    if (lane == 0) red[wvi] = m;
    __syncthreads();
    const float M = fmaxf(fmaxf(red[0], red[1]), fmaxf(red[2], red[3]));
    const float s = fmaxf(M, MINR) / QPF;
    const float rs = 1.0f / s;
    if (tid == 0) { sx[token] = s; amaxh[token] = 0u; }
    if (tid < k4) {
      char4 c;
      c.x = (signed char)(int)rintf(v.x * rs);
      c.y = (signed char)(int)rintf(v.y * rs);
      c.z = (signed char)(int)rintf(v.z * rs);
      c.w = (signed char)(int)rintf(v.w * rs);
      ((char4*)(qx + (size_t)token * K))[tid] = c;
    }
  }
}

// ---------- weight quantize (reduces 512 partials itself; y selects tensor) ----------
__global__ __launch_bounds__(256) void wquant2_kernel(
    const float* __restrict__ w1, const float* __restrict__ w2, int n4,
    const float* __restrict__ partial, unsigned* __restrict__ wamax,
    signed char* __restrict__ q1, signed char* __restrict__ q2) {
  __shared__ float red[4];
  const int tid = threadIdx.x;
  const int lane = tid & 63, wvi = tid >> 6;
  const int y = blockIdx.y;
  float m = fmaxf(partial[y * 512 + tid], partial[y * 512 + 256 + tid]);
  m = wave_max64(m);
  if (lane == 0) red[wvi] = m;
  __syncthreads();
  const float M = fmaxf(fmaxf(red[0], red[1]), fmaxf(red[2], red[3]));
  if (blockIdx.x == 0 && tid == 0) wamax[y] = __float_as_uint(M);
  const float s = fmaxf(M, MINR) / QPF;
  const float rs = 1.0f / s;
  const float4* w4 = (const float4*)(y ? w2 : w1);
  char4* q4 = (char4*)(y ? q2 : q1);
  for (int i = blockIdx.x * 256 + tid; i < n4; i += gridDim.x * 256) {
    float4 v = w4[i];
    char4 c;
    c.x = (signed char)(int)rintf(v.x * rs);
    c.y = (signed char)(int)rintf(v.y * rs);
    c.z = (signed char)(int)rintf(v.z * rs);
    c.w = (signed char)(int)rintf(v.w * rs);
    q4[i] = c;
  }
}

// ---------- per-token h quantize: 4 tokens/block, one wave each ----------
__global__ __launch_bounds__(256) void hquant4_kernel(
    const _Float16* __restrict__ h, const unsigned* __restrict__ amaxbits,
    signed char* __restrict__ qh, float* __restrict__ sh, int K) {
  const int token = blockIdx.x * 4 + (threadIdx.x >> 6);
  const int lane = threadIdx.x & 63;
  const float s = fmaxf(__uint_as_float(amaxbits[token]), MINR) / QPF;
  const float rs = 1.0f / s;
  if (lane == 0) sh[token] = s;
  const h8* hr = (const h8*)(h + (size_t)token * K);
  c8* qr = (c8*)(qh + (size_t)token * K);
  for (int i = lane; i < (K >> 3); i += 64) {
    h8 v = hr[i];
    c8 c;
#pragma unroll
    for (int j = 0; j < 8; j++)
      c[j] = (signed char)(int)rintf((float)v[j] * rs);
    qr[i] = c;
  }
}

// ---------- GEMM1: h[n][m] = gelu((qx·qw1^T + b1)·sx·sw1), f16 out + row amax ----------
// 128x128 tile, BK=64, 4 waves 2x2, XOR-swizzled LDS, 3-buffer vmcnt(4) pipeline.
// Epilogue: gelu+amax in regs, transpose through LDS (stride 136 f16), coalesced
// dwordx4 stores.
__global__ __launch_bounds__(256, 2) void gemm1_i8(
    const signed char* __restrict__ A, const signed char* __restrict__ B,
    const float* __restrict__ bias, const float* __restrict__ sA,
    const unsigned* __restrict__ sBbits, _Float16* __restrict__ out,
    unsigned* __restrict__ amax_out, int N, int K, int Mout) {
  __shared__ __align__(16) signed char lds[3 * 16384];

  const int t = threadIdx.x;
  const int lane = t & 63;
  const int wv = t >> 6;
  const int wm = wv >> 1;
  const int wn = wv & 1;
  const int rowBlk = blockIdx.y * 128;
  const int colBlk = blockIdx.x * 128;

  int ar0 = rowBlk + wv * 16 + (lane >> 2);
  int ar1 = ar0 + 64;
  if (ar0 > N - 1) ar0 = N - 1;
  if (ar1 > N - 1) ar1 = N - 1;
  const int br0 = colBlk + wv * 16 + (lane >> 2);
  const int br1 = br0 + 64;
  const int kb = (((lane & 3) ^ ((lane >> 3) & 3)) * 16);

  const signed char* gA0 = A + (size_t)ar0 * K + kb;
  const signed char* gA1 = A + (size_t)ar1 * K + kb;
  const signed char* gB0 = B + (size_t)br0 * K + kb;
  const signed char* gB1 = B + (size_t)br1 * K + kb;

  const v4i vzero = {0, 0, 0, 0};
  v4i acc[4][4];
#pragma unroll
  for (int i = 0; i < 4; i++)
#pragma unroll
    for (int j = 0; j < 4; j++) acc[i][j] = vzero;

  const int swz = ((lane >> 4) ^ ((lane >> 1) & 3)) * 16;
  const int aoff = (wm * 64 + (lane & 15)) * 64 + swz;
  const int boff = (wn * 64 + (lane & 15)) * 64 + swz + 8192;

  const int T = K >> 6;

  auto issue = [&](int bufo) {
    signed char* a = lds + bufo + wv * 1024;
    gl2lds16(gA0, a);
    gl2lds16(gA1, a + 4096);
    gl2lds16(gB0, a + 8192);
    gl2lds16(gB1, a + 12288);
    gA0 += 64; gA1 += 64; gB0 += 64; gB1 += 64;
  };

  issue(0);
  issue(16384);

  int cur = 0;
  for (int kt = 0; kt < T; ++kt) {
    asm volatile("" ::: "memory");
    if (kt < T - 1)
      __builtin_amdgcn_s_waitcnt(0x0074);  // vmcnt(4) lgkmcnt(0)
    else
      __builtin_amdgcn_s_waitcnt(0x0070);  // vmcnt(0) lgkmcnt(0)
    __builtin_amdgcn_s_barrier();
    asm volatile("" ::: "memory");

    if (kt + 2 < T) {
      int pf = cur + 32768;
      if (pf >= 49152) pf -= 49152;
      issue(pf);
    }

    v4i a[4], b[4];
#pragma unroll
    for (int mi = 0; mi < 4; mi++)
      a[mi] = *(const v4i*)(lds + cur + aoff + mi * 1024);
#pragma unroll
    for (int ni = 0; ni < 4; ni++)
      b[ni] = *(const v4i*)(lds + cur + boff + ni * 1024);
#pragma unroll
    for (int mi = 0; mi < 4; mi++)
#pragma unroll
      for (int ni = 0; ni < 4; ni++)
        acc[mi][ni] = __builtin_amdgcn_mfma_i32_16x16x64_i8(a[mi], b[ni],
                                                            acc[mi][ni], 0, 0, 0);
    cur += 16384;
    if (cur >= 49152) cur = 0;
  }

  // ---- epilogue ----
  const float sB = fmaxf(__uint_as_float(*sBbits), MINR) / QPF;
  const int colb = wn * 64 + (lane & 15);         // local col
  const int rowb = wm * 64 + (lane >> 4) * 4;     // local row

  float bv[4];
#pragma unroll
  for (int ni = 0; ni < 4; ni++) bv[ni] = bias[colBlk + colb + ni * 16];

  __syncthreads();   // all waves done reading staging LDS; reuse as Hs
  _Float16* Hs = (_Float16*)lds;   // stride 136 f16 (272 B, 16B-aligned)

#pragma unroll
  for (int mi = 0; mi < 4; mi++) {
    const int lrow0 = rowb + mi * 16;
    const int grow0 = rowBlk + lrow0;
    float sAv[4];
#pragma unroll
    for (int r = 0; r < 4; r++) sAv[r] = (grow0 + r < N) ? sA[grow0 + r] : 0.f;
    float rmax[4] = {0.f, 0.f, 0.f, 0.f};
#pragma unroll
    for (int ni = 0; ni < 4; ni++) {
#pragma unroll
      for (int r = 0; r < 4; r++) {
        float v = ((float)acc[mi][ni][r] + bv[ni]) * (sAv[r] * sB);
        v = gelu_exact(v);
        rmax[r] = fmaxf(rmax[r], fabsf(v));
        Hs[(lrow0 + r) * 136 + colb + ni * 16] = (_Float16)v;
      }
    }
#pragma unroll
    for (int r = 0; r < 4; r++) {
      float m = rmax[r];
      m = fmaxf(m, __shfl_xor(m, 1, 64));
      m = fmaxf(m, __shfl_xor(m, 2, 64));
      m = fmaxf(m, __shfl_xor(m, 4, 64));
      m = fmaxf(m, __shfl_xor(m, 8, 64));
      if ((lane & 15) == 0 && grow0 + r < N)
        atomicMax(amax_out + grow0 + r, __float_as_uint(m));
    }
  }
  __syncthreads();
  // coalesced read-back: thread t -> row t>>1, col half (t&1)*64
  {
    const int r = t >> 1, hh = t & 1;
    const int grow = rowBlk + r;
    if (grow < N) {
      const v4i* src = (const v4i*)((const signed char*)lds + r * 272 + hh * 128);
      v4i* dst = (v4i*)(out + (size_t)grow * Mout + colBlk + hh * 64);
#pragma unroll
      for (int j = 0; j < 8; j++) dst[j] = src[j];
    }
  }
}

// ---------- GEMM2: out[n][m] = (qh·qw2^T + b2)·sh·sw2, f32 out ----------
// 128x64 tile, 128 threads (2 waves, each 64 rows x 64 cols), BK=64,
// 3-buffer vmcnt(6) pipeline, LDS-transpose coalesced f32 epilogue.
__global__ __launch_bounds__(128, 2) void gemm2_i8(
    const signed char* __restrict__ A, const signed char* __restrict__ B,
    const float* __restrict__ bias, const float* __restrict__ sA,
    const unsigned* __restrict__ sBbits, float* __restrict__ out,
    int N, int K, int Mout) {
  __shared__ __align__(16) signed char lds[3 * 12288];  // per buf: A 8K | B 4K

  const int t = threadIdx.x;
  const int lane = t & 63;
  const int wv = t >> 6;    // 0..1: row half
  const int rowBlk = blockIdx.y * 128;
  const int colBlk = blockIdx.x * 64;

  const int trow = t >> 2;                                // 0..31
  const int kb = (((t & 3) ^ ((t >> 3) & 3)) * 16);       // swizzled chunk

  int ar[4];
#pragma unroll
  for (int i = 0; i < 4; i++) {
    ar[i] = rowBlk + i * 32 + trow;
    if (ar[i] > N - 1) ar[i] = N - 1;
  }
  const signed char* gA0 = A + (size_t)ar[0] * K + kb;
  const signed char* gA1 = A + (size_t)ar[1] * K + kb;
  const signed char* gA2 = A + (size_t)ar[2] * K + kb;
  const signed char* gA3 = A + (size_t)ar[3] * K + kb;
  const signed char* gB0 = B + (size_t)(colBlk + trow) * K + kb;
  const signed char* gB1 = B + (size_t)(colBlk + 32 + trow) * K + kb;

  const v4i vzero = {0, 0, 0, 0};
  v4i acc[4][4];
#pragma unroll
  for (int i = 0; i < 4; i++)
#pragma unroll
    for (int j = 0; j < 4; j++) acc[i][j] = vzero;

  const int swz = ((lane >> 4) ^ ((lane >> 1) & 3)) * 16;
  const int aoff = (wv * 64 + (lane & 15)) * 64 + swz;
  const int boff = 8192 + (lane & 15) * 64 + swz;

  const int T = K >> 6;

  auto issue = [&](int bufo) {
    signed char* p = lds + bufo + t * 16;
    gl2lds16(gA0, p);
    gl2lds16(gA1, p + 2048);
    gl2lds16(gA2, p + 4096);
    gl2lds16(gA3, p + 6144);
    gl2lds16(gB0, p + 8192);
    gl2lds16(gB1, p + 10240);
    gA0 += 64; gA1 += 64; gA2 += 64; gA3 += 64; gB0 += 64; gB1 += 64;
  };

  issue(0);
  issue(12288);

  int cur = 0;
  for (int kt = 0; kt < T; ++kt) {
    asm volatile("" ::: "memory");
    if (kt < T - 1)
      __builtin_amdgcn_s_waitcnt(0x0076);  // vmcnt(6) lgkmcnt(0)
    else
      __builtin_amdgcn_s_waitcnt(0x0070);
    __builtin_amdgcn_s_barrier();
    asm volatile("" ::: "memory");

    if (kt + 2 < T) {
      int pf = cur + 24576;
      if (pf >= 36864) pf -= 36864;
      issue(pf);
    }

    v4i a[4], b[4];
#pragma unroll
    for (int mi = 0; mi < 4; mi++)
      a[mi] = *(const v4i*)(lds + cur + aoff + mi * 1024);
#pragma unroll
    for (int ni = 0; ni < 4; ni++)
      b[ni] = *(const v4i*)(lds + cur + boff + ni * 1024);
#pragma unroll
    for (int mi = 0; mi < 4; mi++)
#pragma unroll
      for (int ni = 0; ni < 4; ni++)
        acc[mi][ni] = __builtin_amdgcn_mfma_i32_16x16x64_i8(a[mi], b[ni],
                                                            acc[mi][ni], 0, 0, 0);
    cur += 12288;
    if (cur >= 36864) cur = 0;
  }

  // ---- epilogue: transpose through LDS (f32, stride 66 dwords), coalesced ----
  const float sB = fmaxf(__uint_as_float(*sBbits), MINR) / QPF;
  const int colb = lane & 15;
  const int rowb = wv * 64 + (lane >> 4) * 4;

  float bv[4];
#pragma unroll
  for (int ni = 0; ni < 4; ni++) bv[ni] = bias[colBlk + colb + ni * 16];

  __syncthreads();
  float* Cs = (float*)lds;   // 128 x (stride 66) floats = 33792 B

#pragma unroll
  for (int mi = 0; mi < 4; mi++) {
    const int lrow0 = rowb + mi * 16;
    const int grow0 = rowBlk + lrow0;
    float sAv[4];
#pragma unroll
    for (int r = 0; r < 4; r++) sAv[r] = (grow0 + r < N) ? sA[grow0 + r] : 0.f;
#pragma unroll
    for (int ni = 0; ni < 4; ni++)
#pragma unroll
      for (int r = 0; r < 4; r++)
        Cs[(lrow0 + r) * 66 + colb + ni * 16] =
            ((float)acc[mi][ni][r] + bv[ni]) * (sAv[r] * sB);
  }
  __syncthreads();
  // thread t -> row t (128 rows), 64 f32 = 16 dwordx4
  {
    const int grow = rowBlk + t;
    if (grow < N) {
      const v4i* src = (const v4i*)(Cs + t * 66);
      v4i* dst = (v4i*)(out + (size_t)grow * Mout + colBlk);
#pragma unroll
      for (int j = 0; j < 16; j++) dst[j] = src[j];
    }
  }
}

extern "C" void kernel_launch(void* const* d_in, const int* in_sizes, int n_in,
                              void* d_out, int out_size, void* d_ws, size_t ws_size,
                              hipStream_t stream) {
  const float* x  = (const float*)d_in[0];
  const float* w1 = (const float*)d_in[1];
  const float* b1 = (const float*)d_in[2];
  const float* w2 = (const float*)d_in[3];
  const float* b2 = (const float*)d_in[4];

  const int H = in_sizes[2];        // 3072
  const int D = in_sizes[4];        // 768
  const int N = in_sizes[0] / D;    // 12608 tokens
  float* out = (float*)d_out;

  char* ws = (char*)d_ws;
  auto alloc = [&](size_t bytes) {
    char* p = ws;
    ws += (bytes + 255) & ~(size_t)255;
    return p;
  };
  signed char* qx  = (signed char*)alloc((size_t)N * D);
  signed char* qw1 = (signed char*)alloc((size_t)H * D);
  signed char* qw2 = (signed char*)alloc((size_t)H * D);
  signed char* qh  = (signed char*)alloc((size_t)N * H);
  float*    sx     = (float*)alloc((size_t)N * 4);
  float*    sh     = (float*)alloc((size_t)N * 4);
  unsigned* amaxh  = (unsigned*)alloc((size_t)N * 4);
  unsigned* wamax  = (unsigned*)alloc(256);
  float*    partial= (float*)alloc(1024 * 4);
  _Float16* h      = (_Float16*)alloc((size_t)N * H * 2);
  (void)ws_size;

  const int n4w = (H * D) >> 2;

  // no memsets needed: partials/wamax are plain-written before use;
  // amaxh zeroed inside pre_kernel (token blocks) before gemm1's atomics.
  pre_kernel<<<1024 + N, 256, 0, stream>>>(w1, w2, n4w, x, qx, sx, amaxh,
                                           partial, D, N);
  wquant2_kernel<<<dim3(512, 2), 256, 0, stream>>>(w1, w2, n4w, partial, wamax,
                                                   qw1, qw2);

  dim3 g1(H / 128, (N + 127) / 128);
  gemm1_i8<<<g1, 256, 0, stream>>>(qx, qw1, b1, sx, wamax + 0, h, amaxh,
                                   N, D, H);
  hquant4_kernel<<<N / 4, 256, 0, stream>>>(h, amaxh, qh, sh, H);

  dim3 g2(D / 64, (N + 127) / 128);
  gemm2_i8<<<g2, 128, 0, stream>>>(qh, qw2, b2, sh, wamax + 1, out, N, H, D);
}

// Round 6
// 256.234 us; speedup vs baseline: 1.0974x; 1.0974x over previous
//
#include <hip/hip_runtime.h>
#include <stdint.h>

#define QPF  127.0f
#define MINR 1e-6f

typedef int v4i __attribute__((ext_vector_type(4)));
typedef float f4v __attribute__((ext_vector_type(4)));
typedef _Float16 h4v __attribute__((ext_vector_type(4)));
typedef _Float16 h8 __attribute__((ext_vector_type(8)));
typedef signed char c8 __attribute__((ext_vector_type(8)));

// ---------- helpers ----------
__device__ __forceinline__ float wave_max64(float v) {
  v = fmaxf(v, __shfl_xor(v, 32, 64));
  v = fmaxf(v, __shfl_xor(v, 16, 64));
  v = fmaxf(v, __shfl_xor(v, 8, 64));
  v = fmaxf(v, __shfl_xor(v, 4, 64));
  v = fmaxf(v, __shfl_xor(v, 2, 64));
  v = fmaxf(v, __shfl_xor(v, 1, 64));
  return v;
}

// Exact-GELU via A&S 7.1.26 erf (|eps| <= 1.5e-7), branchless.
__device__ __forceinline__ float gelu_exact(float x) {
  float z = fabsf(x) * 0.70710678118654752440f;
  float t = __builtin_amdgcn_rcpf(fmaf(0.3275911f, z, 1.0f));
  float p = fmaf(fmaf(fmaf(fmaf(1.061405429f, t, -1.453152027f), t,
                           1.421413741f), t, -0.284496736f), t, 0.254829592f) * t;
  float e = __expf(-z * z);
  float erfz = fmaf(-p, e, 1.0f);
  float cdf = fmaf(0.5f, copysignf(erfz, x), 0.5f);
  return x * cdf;
}

// async global->LDS, 16B per lane; LDS dest is wave-uniform base + lane*16
__device__ __forceinline__ void gl2lds16(const void* g, void* l) {
  __builtin_amdgcn_global_load_lds(
      (const __attribute__((address_space(1))) int*)g,
      (__attribute__((address_space(3))) int*)l,
      16, 0, 0);
}

// ---------- fused pre-pass: w1/w2 amax partials + per-token x quant + amaxh zero ----
__global__ __launch_bounds__(256) void pre_kernel(
    const float* __restrict__ w1, const float* __restrict__ w2, int n4,
    const float* __restrict__ x, signed char* __restrict__ qx,
    float* __restrict__ sx, unsigned* __restrict__ amaxh,
    float* __restrict__ partial, int K, int nTok) {
  __shared__ float red[4];
  const int b = blockIdx.x;
  const int tid = threadIdx.x;
  const int lane = tid & 63, wvi = tid >> 6;

  if (b < 1024) {
    const float4* w4 = (const float4*)(b < 512 ? w1 : w2);
    const int bb = b & 511;
    float m = 0.f;
    for (int i = bb * 256 + tid; i < n4; i += 512 * 256) {
      float4 v = w4[i];
      m = fmaxf(m, fmaxf(fmaxf(fabsf(v.x), fabsf(v.y)),
                         fmaxf(fabsf(v.z), fabsf(v.w))));
    }
    m = wave_max64(m);
    if (lane == 0) red[wvi] = m;
    __syncthreads();
    if (tid == 0)
      partial[b] = fmaxf(fmaxf(red[0], red[1]), fmaxf(red[2], red[3]));
  } else {
    const int token = b - 1024;
    const float4* xr = (const float4*)(x + (size_t)token * K);
    const int k4 = K >> 2;   // 192
    float m = 0.f;
    float4 v = {0.f, 0.f, 0.f, 0.f};
    if (tid < k4) {
      v = xr[tid];
      m = fmaxf(fmaxf(fabsf(v.x), fabsf(v.y)), fmaxf(fabsf(v.z), fabsf(v.w)));
    }
    m = wave_max64(m);
    if (lane == 0) red[wvi] = m;
    __syncthreads();
    const float M = fmaxf(fmaxf(red[0], red[1]), fmaxf(red[2], red[3]));
    const float s = fmaxf(M, MINR) / QPF;
    const float rs = 1.0f / s;
    if (tid == 0) { sx[token] = s; amaxh[token] = 0u; }
    if (tid < k4) {
      char4 c;
      c.x = (signed char)(int)rintf(v.x * rs);
      c.y = (signed char)(int)rintf(v.y * rs);
      c.z = (signed char)(int)rintf(v.z * rs);
      c.w = (signed char)(int)rintf(v.w * rs);
      ((char4*)(qx + (size_t)token * K))[tid] = c;
    }
  }
}

// ---------- weight quantize (reduces 512 partials itself; y selects tensor) ----------
__global__ __launch_bounds__(256) void wquant2_kernel(
    const float* __restrict__ w1, const float* __restrict__ w2, int n4,
    const float* __restrict__ partial, unsigned* __restrict__ wamax,
    signed char* __restrict__ q1, signed char* __restrict__ q2) {
  __shared__ float red[4];
  const int tid = threadIdx.x;
  const int lane = tid & 63, wvi = tid >> 6;
  const int y = blockIdx.y;
  float m = fmaxf(partial[y * 512 + tid], partial[y * 512 + 256 + tid]);
  m = wave_max64(m);
  if (lane == 0) red[wvi] = m;
  __syncthreads();
  const float M = fmaxf(fmaxf(red[0], red[1]), fmaxf(red[2], red[3]));
  if (blockIdx.x == 0 && tid == 0) wamax[y] = __float_as_uint(M);
  const float s = fmaxf(M, MINR) / QPF;
  const float rs = 1.0f / s;
  const float4* w4 = (const float4*)(y ? w2 : w1);
  char4* q4 = (char4*)(y ? q2 : q1);
  for (int i = blockIdx.x * 256 + tid; i < n4; i += gridDim.x * 256) {
    float4 v = w4[i];
    char4 c;
    c.x = (signed char)(int)rintf(v.x * rs);
    c.y = (signed char)(int)rintf(v.y * rs);
    c.z = (signed char)(int)rintf(v.z * rs);
    c.w = (signed char)(int)rintf(v.w * rs);
    q4[i] = c;
  }
}

// ---------- per-token h quantize: 4 tokens/block, one wave each ----------
__global__ __launch_bounds__(256) void hquant4_kernel(
    const _Float16* __restrict__ h, const unsigned* __restrict__ amaxbits,
    signed char* __restrict__ qh, float* __restrict__ sh, int K) {
  const int token = blockIdx.x * 4 + (threadIdx.x >> 6);
  const int lane = threadIdx.x & 63;
  const float s = fmaxf(__uint_as_float(amaxbits[token]), MINR) / QPF;
  const float rs = 1.0f / s;
  if (lane == 0) sh[token] = s;
  const h8* hr = (const h8*)(h + (size_t)token * K);
  c8* qr = (c8*)(qh + (size_t)token * K);
  for (int i = lane; i < (K >> 3); i += 64) {
    h8 v = hr[i];
    c8 c;
#pragma unroll
    for (int j = 0; j < 8; j++)
      c[j] = (signed char)(int)rintf((float)v[j] * rs);
    qr[i] = c;
  }
}

// ---------- GEMM1: h = gelu((qx·qw1^T + b1)·sx·sw1), f16 out + per-row amax ----------
// 128x128 tile, BK=64, 4 waves 2x2, XOR-swizzled LDS, 3-buffer vmcnt(4) pipeline.
// OPERAND-SWAPPED MFMA: D = (w-frag)·(x-frag) so a lane's 4 acc regs are 4
// CONSECUTIVE OUTPUT COLUMNS of one token -> direct 8B f16 stores, no transpose.
__global__ __launch_bounds__(256, 2) void gemm1_i8(
    const signed char* __restrict__ A, const signed char* __restrict__ B,
    const float* __restrict__ bias, const float* __restrict__ sA,
    const unsigned* __restrict__ sBbits, _Float16* __restrict__ out,
    unsigned* __restrict__ amax_out, int N, int K, int Mout) {
  __shared__ __align__(16) signed char lds[3 * 16384];

  const int t = threadIdx.x;
  const int lane = t & 63;
  const int wv = t >> 6;
  const int wm = wv >> 1;
  const int wn = wv & 1;
  const int rowBlk = blockIdx.y * 128;
  const int colBlk = blockIdx.x * 128;

  int ar0 = rowBlk + wv * 16 + (lane >> 2);
  int ar1 = ar0 + 64;
  if (ar0 > N - 1) ar0 = N - 1;
  if (ar1 > N - 1) ar1 = N - 1;
  const int br0 = colBlk + wv * 16 + (lane >> 2);
  const int br1 = br0 + 64;
  const int kb = (((lane & 3) ^ ((lane >> 3) & 3)) * 16);

  const signed char* gA0 = A + (size_t)ar0 * K + kb;
  const signed char* gA1 = A + (size_t)ar1 * K + kb;
  const signed char* gB0 = B + (size_t)br0 * K + kb;
  const signed char* gB1 = B + (size_t)br1 * K + kb;

  const v4i vzero = {0, 0, 0, 0};
  v4i acc[4][4];
#pragma unroll
  for (int i = 0; i < 4; i++)
#pragma unroll
    for (int j = 0; j < 4; j++) acc[i][j] = vzero;

  const int swz = ((lane >> 4) ^ ((lane >> 1) & 3)) * 16;
  const int aoff = (wm * 64 + (lane & 15)) * 64 + swz;
  const int boff = (wn * 64 + (lane & 15)) * 64 + swz + 8192;

  const int T = K >> 6;

  auto issue = [&](int bufo) {
    signed char* a = lds + bufo + wv * 1024;
    gl2lds16(gA0, a);
    gl2lds16(gA1, a + 4096);
    gl2lds16(gB0, a + 8192);
    gl2lds16(gB1, a + 12288);
    gA0 += 64; gA1 += 64; gB0 += 64; gB1 += 64;
  };

  issue(0);
  issue(16384);

  int cur = 0;
  for (int kt = 0; kt < T; ++kt) {
    asm volatile("" ::: "memory");
    if (kt < T - 1)
      __builtin_amdgcn_s_waitcnt(0x0074);  // vmcnt(4) lgkmcnt(0)
    else
      __builtin_amdgcn_s_waitcnt(0x0070);  // vmcnt(0) lgkmcnt(0)
    __builtin_amdgcn_s_barrier();
    asm volatile("" ::: "memory");

    if (kt + 2 < T) {
      int pf = cur + 32768;
      if (pf >= 49152) pf -= 49152;
      issue(pf);
    }

    v4i a[4], b[4];
#pragma unroll
    for (int mi = 0; mi < 4; mi++)
      a[mi] = *(const v4i*)(lds + cur + aoff + mi * 1024);
#pragma unroll
    for (int ni = 0; ni < 4; ni++)
      b[ni] = *(const v4i*)(lds + cur + boff + ni * 1024);
    // swapped operands: acc cols <- token (lane&15), acc rows <- weight col
#pragma unroll
    for (int mi = 0; mi < 4; mi++)
#pragma unroll
      for (int ni = 0; ni < 4; ni++)
        acc[mi][ni] = __builtin_amdgcn_mfma_i32_16x16x64_i8(b[ni], a[mi],
                                                            acc[mi][ni], 0, 0, 0);
    cur += 16384;
    if (cur >= 49152) cur = 0;
  }

  // ---- epilogue: lane owns token (rowBlk+wm*64+mi*16+(lane&15)),
  //      cols col0+ni*16 .. +3 where col0 = colBlk+wn*64+quad*4 ----
  const float sB = fmaxf(__uint_as_float(*sBbits), MINR) / QPF;
  const int col0 = colBlk + wn * 64 + (lane >> 4) * 4;

  f4v bv[4];
#pragma unroll
  for (int ni = 0; ni < 4; ni++) bv[ni] = *(const f4v*)(bias + col0 + ni * 16);

#pragma unroll
  for (int mi = 0; mi < 4; mi++) {
    const int grow = rowBlk + wm * 64 + mi * 16 + (lane & 15);
    const float ss = ((grow < N) ? sA[grow] : 0.f) * sB;
    float rmax = 0.f;
#pragma unroll
    for (int ni = 0; ni < 4; ni++) {
      h4v hv;
#pragma unroll
      for (int r = 0; r < 4; r++) {
        float v = ((float)acc[mi][ni][r] + bv[ni][r]) * ss;
        v = gelu_exact(v);
        rmax = fmaxf(rmax, fabsf(v));
        hv[r] = (_Float16)v;
      }
      if (grow < N)
        *(h4v*)(out + (size_t)grow * Mout + col0 + ni * 16) = hv;
    }
    rmax = fmaxf(rmax, __shfl_xor(rmax, 16, 64));
    rmax = fmaxf(rmax, __shfl_xor(rmax, 32, 64));
    if (lane < 16 && grow < N)
      atomicMax(amax_out + grow, __float_as_uint(rmax));
  }
}

// ---------- GEMM2: out = (qh·qw2^T + b2)·sh·sw2, f32 out ----------
// 128x64 tile, 128 threads (2 waves, each 64x64), BK=64, 3-buffer vmcnt(6)
// pipeline. Operand-swapped MFMA -> direct dwordx4 f32 stores.
__global__ __launch_bounds__(128, 2) void gemm2_i8(
    const signed char* __restrict__ A, const signed char* __restrict__ B,
    const float* __restrict__ bias, const float* __restrict__ sA,
    const unsigned* __restrict__ sBbits, float* __restrict__ out,
    int N, int K, int Mout) {
  __shared__ __align__(16) signed char lds[3 * 12288];  // per buf: A 8K | B 4K

  const int t = threadIdx.x;
  const int lane = t & 63;
  const int wv = t >> 6;    // row half
  const int rowBlk = blockIdx.y * 128;
  const int colBlk = blockIdx.x * 64;

  const int trow = t >> 2;
  const int kb = (((t & 3) ^ ((t >> 3) & 3)) * 16);

  int ar[4];
#pragma unroll
  for (int i = 0; i < 4; i++) {
    ar[i] = rowBlk + i * 32 + trow;
    if (ar[i] > N - 1) ar[i] = N - 1;
  }
  const signed char* gA0 = A + (size_t)ar[0] * K + kb;
  const signed char* gA1 = A + (size_t)ar[1] * K + kb;
  const signed char* gA2 = A + (size_t)ar[2] * K + kb;
  const signed char* gA3 = A + (size_t)ar[3] * K + kb;
  const signed char* gB0 = B + (size_t)(colBlk + trow) * K + kb;
  const signed char* gB1 = B + (size_t)(colBlk + 32 + trow) * K + kb;

  const v4i vzero = {0, 0, 0, 0};
  v4i acc[4][4];
#pragma unroll
  for (int i = 0; i < 4; i++)
#pragma unroll
    for (int j = 0; j < 4; j++) acc[i][j] = vzero;

  const int swz = ((lane >> 4) ^ ((lane >> 1) & 3)) * 16;
  const int aoff = (wv * 64 + (lane & 15)) * 64 + swz;
  const int boff = 8192 + (lane & 15) * 64 + swz;

  const int T = K >> 6;

  auto issue = [&](int bufo) {
    signed char* p = lds + bufo + t * 16;
    gl2lds16(gA0, p);
    gl2lds16(gA1, p + 2048);
    gl2lds16(gA2, p + 4096);
    gl2lds16(gA3, p + 6144);
    gl2lds16(gB0, p + 8192);
    gl2lds16(gB1, p + 10240);
    gA0 += 64; gA1 += 64; gA2 += 64; gA3 += 64; gB0 += 64; gB1 += 64;
  };

  issue(0);
  issue(12288);

  int cur = 0;
  for (int kt = 0; kt < T; ++kt) {
    asm volatile("" ::: "memory");
    if (kt < T - 1)
      __builtin_amdgcn_s_waitcnt(0x0076);  // vmcnt(6) lgkmcnt(0)
    else
      __builtin_amdgcn_s_waitcnt(0x0070);
    __builtin_amdgcn_s_barrier();
    asm volatile("" ::: "memory");

    if (kt + 2 < T) {
      int pf = cur + 24576;
      if (pf >= 36864) pf -= 36864;
      issue(pf);
    }

    v4i a[4], b[4];
#pragma unroll
    for (int mi = 0; mi < 4; mi++)
      a[mi] = *(const v4i*)(lds + cur + aoff + mi * 1024);
#pragma unroll
    for (int ni = 0; ni < 4; ni++)
      b[ni] = *(const v4i*)(lds + cur + boff + ni * 1024);
#pragma unroll
    for (int mi = 0; mi < 4; mi++)
#pragma unroll
      for (int ni = 0; ni < 4; ni++)
        acc[mi][ni] = __builtin_amdgcn_mfma_i32_16x16x64_i8(b[ni], a[mi],
                                                            acc[mi][ni], 0, 0, 0);
    cur += 12288;
    if (cur >= 36864) cur = 0;
  }

  // ---- epilogue: direct dwordx4 stores ----
  const float sB = fmaxf(__uint_as_float(*sBbits), MINR) / QPF;
  const int col0 = colBlk + (lane >> 4) * 4;

  f4v bv[4];
#pragma unroll
  for (int ni = 0; ni < 4; ni++) bv[ni] = *(const f4v*)(bias + col0 + ni * 16);

#pragma unroll
  for (int mi = 0; mi < 4; mi++) {
    const int grow = rowBlk + wv * 64 + mi * 16 + (lane & 15);
    const float ss = ((grow < N) ? sA[grow] : 0.f) * sB;
#pragma unroll
    for (int ni = 0; ni < 4; ni++) {
      f4v o;
#pragma unroll
      for (int r = 0; r < 4; r++)
        o[r] = ((float)acc[mi][ni][r] + bv[ni][r]) * ss;
      if (grow < N)
        *(f4v*)(out + (size_t)grow * Mout + col0 + ni * 16) = o;
    }
  }
}

extern "C" void kernel_launch(void* const* d_in, const int* in_sizes, int n_in,
                              void* d_out, int out_size, void* d_ws, size_t ws_size,
                              hipStream_t stream) {
  const float* x  = (const float*)d_in[0];
  const float* w1 = (const float*)d_in[1];
  const float* b1 = (const float*)d_in[2];
  const float* w2 = (const float*)d_in[3];
  const float* b2 = (const float*)d_in[4];

  const int H = in_sizes[2];        // 3072
  const int D = in_sizes[4];        // 768
  const int N = in_sizes[0] / D;    // 12608 tokens
  float* out = (float*)d_out;

  char* ws = (char*)d_ws;
  auto alloc = [&](size_t bytes) {
    char* p = ws;
    ws += (bytes + 255) & ~(size_t)255;
    return p;
  };
  signed char* qx  = (signed char*)alloc((size_t)N * D);
  signed char* qw1 = (signed char*)alloc((size_t)H * D);
  signed char* qw2 = (signed char*)alloc((size_t)H * D);
  signed char* qh  = (signed char*)alloc((size_t)N * H);
  float*    sx     = (float*)alloc((size_t)N * 4);
  float*    sh     = (float*)alloc((size_t)N * 4);
  unsigned* amaxh  = (unsigned*)alloc((size_t)N * 4);
  unsigned* wamax  = (unsigned*)alloc(256);
  float*    partial= (float*)alloc(1024 * 4);
  _Float16* h      = (_Float16*)alloc((size_t)N * H * 2);
  (void)ws_size;

  const int n4w = (H * D) >> 2;

  pre_kernel<<<1024 + N, 256, 0, stream>>>(w1, w2, n4w, x, qx, sx, amaxh,
                                           partial, D, N);
  wquant2_kernel<<<dim3(512, 2), 256, 0, stream>>>(w1, w2, n4w, partial, wamax,
                                                   qw1, qw2);

  dim3 g1(H / 128, (N + 127) / 128);
  gemm1_i8<<<g1, 256, 0, stream>>>(qx, qw1, b1, sx, wamax + 0, h, amaxh,
                                   N, D, H);
  hquant4_kernel<<<N / 4, 256, 0, stream>>>(h, amaxh, qh, sh, H);

  dim3 g2(D / 64, (N + 127) / 128);
  gemm2_i8<<<g2, 128, 0, stream>>>(qh, qw2, b2, sh, wamax + 1, out, N, H, D);
}